// Round 10
// baseline (89.376 us; speedup 1.0000x reference)
//
#include <hip/hip_runtime.h>

#define HH 2160
#define WW 3840
#define K 31
#define RAD 15
#define TW 128
#define TH 16
#define IW 160            // staged cols: gx in [x0-16, x0+144)
#define IH 46             // TH + K - 1
#define NTHREADS 512
#define TMPW 164          // padded s_tmp row stride
#define NTX 30            // 3840/128
#define NTY 135           // 2160/16

#define GLDS(gp, lp) __builtin_amdgcn_global_load_lds(                         \
    (const __attribute__((address_space(1))) void*)(gp),                       \
    (__attribute__((address_space(3))) void*)(lp), 16, 0, 0)

__device__ __forceinline__ float fcomp(float4 v, int p) {
    switch (p) { case 0: return v.x; case 1: return v.y; case 2: return v.z; default: return v.w; }
}

__device__ __forceinline__ float uniformf(float x) {
    return __uint_as_float(__builtin_amdgcn_readfirstlane(__float_as_uint(x)));
}

__global__ __launch_bounds__(NTHREADS, 8) void blur_masked_kernel(
    const float* __restrict__ img, const float* __restrict__ mask,
    const float* __restrict__ kern, float* __restrict__ out)
{
    __shared__ float s_in[IH * IW];        // 29.4 KB
    __shared__ float s_tmp[TH * TMPW];     // 10.5 KB
    __shared__ float s_k1[K];

    const int b  = blockIdx.x;
    const int tx = b % NTX;
    const int ty = b / NTX;
    const int x0 = tx * TW;
    const int y0 = ty * TH;
    const int t  = threadIdx.x;

    // thread -> output pixels: row hr, 4 consecutive cols hc0..hc0+3
    const int hr  = t >> 5;         // 0..15
    const int hc0 = (t & 31) * 4;   // 0,4,...,124

    // ---- 1D kernel = row sums of 2D kernel (identical per channel) ----
    if (t < K) {
        float s = 0.f;
        const float* kr = kern + t * K;
        #pragma unroll
        for (int j = 0; j < K; ++j) s += kr[j];
        s_k1[t] = s;
    }

    // ---- mask + unconditional img prefetch (concurrent 16B loads; copy path
    //      uses them directly, blur path reuses them as blend iv) ----
    const size_t HW = (size_t)HH * WW;
    const size_t pix0 = (size_t)(y0 + hr) * WW + (x0 + hc0);
    float4 mv = *(const float4*)(mask + pix0);
    float4 i0 = *(const float4*)(img + pix0);
    float4 i1 = *(const float4*)(img + HW + pix0);
    float4 i2 = *(const float4*)(img + 2 * HW + pix0);

    int anyLocal = (mv.x != 0.f) | (mv.y != 0.f) | (mv.z != 0.f) | (mv.w != 0.f);
    int any = __syncthreads_or(anyLocal);   // also publishes s_k1

    if (!any) {
        // pure copy: out = img * 255, interleave in regs, 3 aligned float4
        float* ob = out + pix0 * 3;
        *(float4*)(ob)     = make_float4(i0.x * 255.f, i1.x * 255.f, i2.x * 255.f, i0.y * 255.f);
        *(float4*)(ob + 4) = make_float4(i1.y * 255.f, i2.y * 255.f, i0.z * 255.f, i1.z * 255.f);
        *(float4*)(ob + 8) = make_float4(i2.z * 255.f, i0.w * 255.f, i1.w * 255.f, i2.w * 255.f);
        return;
    }

    // taps -> SGPRs (wave-uniform)
    float k1r[K];
    #pragma unroll
    for (int j = 0; j < K; ++j) k1r[j] = uniformf(s_k1[j]);

    // interior tile: whole halo in-bounds
    const bool interior = (tx >= 1) && (tx <= NTX - 2) && (ty >= 1) && (ty <= NTY - 2);

    // staging mapping: 480 active threads = 12 rows x 40 float4-cols per round
    const int sr  = t / 40;          // 0..11 active (t < 480)
    const int sc  = t % 40;
    const bool sact = (t < 480);

    auto stage = [&](int ch) {
        const float* gp0 = img + (size_t)ch * HW
                         + (size_t)(y0 - RAD + sr) * WW + (x0 - 16 + 4 * sc);
        float* lp0 = s_in + sr * IW + 4 * sc;
        if (interior) {
            if (sact) {
                #pragma unroll
                for (int k2 = 0; k2 < 4; ++k2) {
                    if (sr + 12 * k2 < IH)
                        GLDS(gp0 + (size_t)(12 * k2) * WW, lp0 + 12 * k2 * IW);
                }
            }
        } else {
            #pragma unroll
            for (int k2 = 0; k2 < 4; ++k2) {
                int r = sr + 12 * k2;
                if (sact && r < IH) {
                    int gy = y0 - RAD + r, gx = x0 - 16 + 4 * sc;
                    float4 v = make_float4(0.f, 0.f, 0.f, 0.f);
                    if (gy >= 0 && gy < HH && gx >= 0 && gx < WW)
                        v = *(const float4*)(img + (size_t)ch * HW + (size_t)gy * WW + gx);
                    *(float4*)(s_in + r * IW + 4 * sc) = v;
                }
            }
        }
    };

    stage(0);

    float o[12];   // final interleaved pixels, built per channel

    // V-pass mapping: 320 active threads, each = (column, 8-row half)
    const int vh = (t >= 160) ? 1 : 0;
    const int vc = t - 160 * vh;     // 0..159 for t<320
    const bool vact = (t < 320);

    #pragma unroll
    for (int ch = 0; ch < 3; ++ch) {
        __syncthreads();   // staging(ch) done; prev H-pass s_tmp reads done

        // ---- vertical pass: stream 38 rows once, 8 running accumulators ----
        if (vact) {
            float acc[8] = {0.f, 0.f, 0.f, 0.f, 0.f, 0.f, 0.f, 0.f};
            const int ybase = vh * 8;
            #pragma unroll
            for (int s = 0; s < 38; ++s) {
                float v = s_in[(ybase + s) * IW + vc];
                #pragma unroll
                for (int j = 0; j < 8; ++j) {
                    if (s - j >= 0 && s - j <= 30) acc[j] += v * k1r[s - j];
                }
            }
            #pragma unroll
            for (int j = 0; j < 8; ++j)
                s_tmp[(ybase + j) * TMPW + vc] = acc[j];
        }

        __syncthreads();   // s_tmp ready; s_in free

        if (ch < 2) stage(ch + 1);   // HBM latency hides under H-pass

        // ---- horizontal pass: sliding window, 4 outputs/thread ----
        float a0 = 0.f, a1 = 0.f, a2 = 0.f, a3 = 0.f;
        const float* rowp = s_tmp + hr * TMPW + hc0;
        #pragma unroll
        for (int q = 0; q < 9; ++q) {
            float4 w = *(const float4*)(rowp + 4 * q);
            #pragma unroll
            for (int e = 0; e < 4; ++e) {
                const int idx = 4 * q + e;   // window col offset 0..35
                float v = fcomp(w, e);
                if (idx - 1 >= 0 && idx - 1 <= 30) a0 += v * k1r[idx - 1];
                if (idx - 2 >= 0 && idx - 2 <= 30) a1 += v * k1r[idx - 2];
                if (idx - 3 >= 0 && idx - 3 <= 30) a2 += v * k1r[idx - 3];
                if (idx - 4 >= 0 && idx - 4 <= 30) a3 += v * k1r[idx - 4];
            }
        }

        // ---- blend this channel into interleaved output registers ----
        float4 iv = (ch == 0) ? i0 : (ch == 1) ? i1 : i2;
        float bl[4] = {a0, a1, a2, a3};
        #pragma unroll
        for (int p = 0; p < 4; ++p) {
            float m = fcomp(mv, p);
            o[p * 3 + ch] = (fcomp(iv, p) * (1.f - m) + bl[p] * m) * 255.f;
        }
    }

    // ---- 3 aligned float4 stores (full-line coalesced) ----
    float* ob = out + pix0 * 3;
    *(float4*)(ob)     = make_float4(o[0], o[1], o[2],  o[3]);
    *(float4*)(ob + 4) = make_float4(o[4], o[5], o[6],  o[7]);
    *(float4*)(ob + 8) = make_float4(o[8], o[9], o[10], o[11]);
}

extern "C" void kernel_launch(void* const* d_in, const int* in_sizes, int n_in,
                              void* d_out, int out_size, void* d_ws, size_t ws_size,
                              hipStream_t stream) {
    const float* img  = (const float*)d_in[0];
    const float* mask = (const float*)d_in[1];
    const float* kern = (const float*)d_in[2];
    float* out = (float*)d_out;
    int nblocks = NTX * NTY;  // 30 x 135 = 4050
    blur_masked_kernel<<<nblocks, NTHREADS, 0, stream>>>(img, mask, kern, out);
}

// Round 11
// 75.114 us; speedup vs baseline: 1.1899x; 1.1899x over previous
//
#include <hip/hip_runtime.h>

#define HH 2160
#define WW 3840
#define K 31
#define RAD 15
#define TW 64
#define TH 16
#define IW 96             // staged cols: gx in [x0-16, x0+80)
#define IH 46             // TH + K - 1
#define NTHREADS 256
#define TMPW 100          // padded s_tmp row stride

#define GLDS(gp, lp) __builtin_amdgcn_global_load_lds(                         \
    (const __attribute__((address_space(1))) void*)(gp),                       \
    (__attribute__((address_space(3))) void*)(lp), 16, 0, 0)

__device__ __forceinline__ float fcomp(float4 v, int p) {
    switch (p) { case 0: return v.x; case 1: return v.y; case 2: return v.z; default: return v.w; }
}

__device__ __forceinline__ float uniformf(float x) {
    return __uint_as_float(__builtin_amdgcn_readfirstlane(__float_as_uint(x)));
}

// ---------------- Kernel A: blur tiles only ----------------
__global__ __launch_bounds__(NTHREADS, 4) void blur_kernel(
    const float* __restrict__ img, const float* __restrict__ mask,
    const float* __restrict__ kern, float* __restrict__ out)
{
    __shared__ float s_in[IH * IW];        // 17.25 KB
    __shared__ float s_tmp[TH * TMPW];     // 6.25 KB
    __shared__ float s_k1[K];

    const int b  = blockIdx.x;
    const int tx = b % 60;
    const int ty = b / 60;
    const int x0 = tx * TW;
    const int y0 = ty * TH;
    const int t  = threadIdx.x;

    const int hr  = t >> 4;         // 0..15
    const int hc0 = (t & 15) * 4;   // 0,4,...,60

    // 1D kernel = row sums of 2D kernel (identical per channel)
    if (t < K) {
        float s = 0.f;
        const float* kr = kern + t * K;
        #pragma unroll
        for (int j = 0; j < K; ++j) s += kr[j];
        s_k1[t] = s;
    }

    const size_t HW = (size_t)HH * WW;
    const size_t pix0 = (size_t)(y0 + hr) * WW + (x0 + hc0);
    float4 mv = *(const float4*)(mask + pix0);
    int anyLocal = (mv.x != 0.f) | (mv.y != 0.f) | (mv.z != 0.f) | (mv.w != 0.f);
    int any = __syncthreads_or(anyLocal);   // also publishes s_k1

    if (!any) return;    // copy kernel owns this tile

    // taps -> SGPRs (wave-uniform)
    float k1r[K];
    #pragma unroll
    for (int j = 0; j < K; ++j) k1r[j] = uniformf(s_k1[j]);

    const bool interior = (tx >= 1) && (tx <= 58) && (ty >= 1) && (ty <= 133);

    // staging: 240 active threads = 10 rows x 24 float4-cols per round
    const int sr  = t / 24;
    const int sc  = t % 24;
    const bool sact = (t < 240);

    auto stage = [&](int ch) {
        const float* gp0 = img + (size_t)ch * HW
                         + (size_t)(y0 - RAD + sr) * WW + (x0 - 16 + 4 * sc);
        float* lp0 = s_in + sr * IW + 4 * sc;
        if (interior) {
            if (sact) {
                #pragma unroll
                for (int k2 = 0; k2 < 5; ++k2) {
                    if (sr + 10 * k2 < IH)
                        GLDS(gp0 + (size_t)(10 * k2) * WW, lp0 + 10 * k2 * IW);
                }
            }
        } else {
            #pragma unroll
            for (int k2 = 0; k2 < 5; ++k2) {
                int r = sr + 10 * k2;
                if (sact && r < IH) {
                    int gy = y0 - RAD + r, gx = x0 - 16 + 4 * sc;
                    float4 v = make_float4(0.f, 0.f, 0.f, 0.f);
                    if (gy >= 0 && gy < HH && gx >= 0 && gx < WW)
                        v = *(const float4*)(img + (size_t)ch * HW + (size_t)gy * WW + gx);
                    *(float4*)(s_in + r * IW + 4 * sc) = v;
                }
            }
        }
    };

    stage(0);

    float o[12];

    // V-pass mapping: 192 active threads = (column, 8-row half)
    const int vc = t % 96;
    const int vh = t / 96;

    #pragma unroll
    for (int ch = 0; ch < 3; ++ch) {
        __syncthreads();   // staging(ch) done; prev H-pass s_tmp reads done

        if (vh < 2) {
            float acc[8] = {0.f, 0.f, 0.f, 0.f, 0.f, 0.f, 0.f, 0.f};
            const int ybase = vh * 8;
            #pragma unroll
            for (int s = 0; s < 38; ++s) {
                float v = s_in[(ybase + s) * IW + vc];
                #pragma unroll
                for (int j = 0; j < 8; ++j) {
                    if (s - j >= 0 && s - j <= 30) acc[j] += v * k1r[s - j];
                }
            }
            #pragma unroll
            for (int j = 0; j < 8; ++j)
                s_tmp[(ybase + j) * TMPW + vc] = acc[j];
        }
        // capture img for blend while s_in holds this channel
        float4 iv = *(const float4*)(s_in + (hr + RAD) * IW + hc0 + 16);

        __syncthreads();   // s_tmp ready; s_in free

        if (ch < 2) stage(ch + 1);   // overlaps with H-pass

        float a0 = 0.f, a1 = 0.f, a2 = 0.f, a3 = 0.f;
        const float* rowp = s_tmp + hr * TMPW + hc0;
        #pragma unroll
        for (int q = 0; q < 9; ++q) {
            float4 w = *(const float4*)(rowp + 4 * q);
            #pragma unroll
            for (int e = 0; e < 4; ++e) {
                const int idx = 4 * q + e;
                float v = fcomp(w, e);
                if (idx - 1 >= 0 && idx - 1 <= 30) a0 += v * k1r[idx - 1];
                if (idx - 2 >= 0 && idx - 2 <= 30) a1 += v * k1r[idx - 2];
                if (idx - 3 >= 0 && idx - 3 <= 30) a2 += v * k1r[idx - 3];
                if (idx - 4 >= 0 && idx - 4 <= 30) a3 += v * k1r[idx - 4];
            }
        }

        float bl[4] = {a0, a1, a2, a3};
        #pragma unroll
        for (int p = 0; p < 4; ++p) {
            float m = fcomp(mv, p);
            o[p * 3 + ch] = (fcomp(iv, p) * (1.f - m) + bl[p] * m) * 255.f;
        }
    }

    float* ob = out + pix0 * 3;
    *(float4*)(ob)     = make_float4(o[0], o[1], o[2],  o[3]);
    *(float4*)(ob + 4) = make_float4(o[4], o[5], o[6],  o[7]);
    *(float4*)(ob + 8) = make_float4(o[8], o[9], o[10], o[11]);
}

// ---------------- Kernel B: copy tiles only (pure streaming) ----------------
__global__ __launch_bounds__(NTHREADS) void copy_kernel(
    const float* __restrict__ img, const float* __restrict__ mask,
    float* __restrict__ out)
{
    const int b  = blockIdx.x;
    const int tx = b % 60;
    const int ty = b / 60;
    const int t  = threadIdx.x;
    const int hr  = t >> 4;
    const int hc0 = (t & 15) * 4;

    const size_t HW = (size_t)HH * WW;
    const size_t pix0 = (size_t)(ty * TH + hr) * WW + (tx * TW + hc0);
    float4 mv = *(const float4*)(mask + pix0);
    int anyLocal = (mv.x != 0.f) | (mv.y != 0.f) | (mv.z != 0.f) | (mv.w != 0.f);
    if (__syncthreads_or(anyLocal)) return;   // blur kernel owns this tile

    float4 i0 = *(const float4*)(img + pix0);
    float4 i1 = *(const float4*)(img + HW + pix0);
    float4 i2 = *(const float4*)(img + 2 * HW + pix0);
    float* ob = out + pix0 * 3;
    *(float4*)(ob)     = make_float4(i0.x * 255.f, i1.x * 255.f, i2.x * 255.f, i0.y * 255.f);
    *(float4*)(ob + 4) = make_float4(i1.y * 255.f, i2.y * 255.f, i0.z * 255.f, i1.z * 255.f);
    *(float4*)(ob + 8) = make_float4(i2.z * 255.f, i0.w * 255.f, i1.w * 255.f, i2.w * 255.f);
}

extern "C" void kernel_launch(void* const* d_in, const int* in_sizes, int n_in,
                              void* d_out, int out_size, void* d_ws, size_t ws_size,
                              hipStream_t stream) {
    const float* img  = (const float*)d_in[0];
    const float* mask = (const float*)d_in[1];
    const float* kern = (const float*)d_in[2];
    float* out = (float*)d_out;
    int nblocks = 60 * 135;  // 8100
    blur_kernel<<<nblocks, NTHREADS, 0, stream>>>(img, mask, kern, out);
    copy_kernel<<<nblocks, NTHREADS, 0, stream>>>(img, mask, out);
}

// Round 12
// 59.102 us; speedup vs baseline: 1.5122x; 1.2709x over previous
//
#include <hip/hip_runtime.h>

#define HH 2160
#define WW 3840
#define K 31
#define RAD 15
#define TW 64
#define TH 16
#define IW 96             // staged cols: gx in [x0-16, x0+80)
#define IH 46             // TH + K - 1
#define NTHREADS 256
#define TSTR 17           // transposed s_tmp stride (odd -> conflict-free)

#define GLDS(gp, lp) __builtin_amdgcn_global_load_lds(                         \
    (const __attribute__((address_space(1))) void*)(gp),                       \
    (__attribute__((address_space(3))) void*)(lp), 16, 0, 0)

__device__ __forceinline__ float fcomp(float4 v, int p) {
    switch (p) { case 0: return v.x; case 1: return v.y; case 2: return v.z; default: return v.w; }
}

__device__ __forceinline__ float uniformf(float x) {
    return __uint_as_float(__builtin_amdgcn_readfirstlane(__float_as_uint(x)));
}

__global__ __launch_bounds__(NTHREADS, 4) void blur_masked_kernel(
    const float* __restrict__ img, const float* __restrict__ mask,
    const float* __restrict__ kern, float* __restrict__ out)
{
    __shared__ float s_in[IH * IW];        // 17.25 KB
    __shared__ float s_tmpT[IW * TSTR];    // transposed V-output, 6.4 KB
    __shared__ float s_k1[K];

    const int b  = blockIdx.x;
    const int tx = b % 60;
    const int ty = b / 60;
    const int x0 = tx * TW;
    const int y0 = ty * TH;
    const int t  = threadIdx.x;

    // thread -> output pixels: row hr, 4 consecutive cols hc0..hc0+3
    const int hr  = t >> 4;         // 0..15
    const int hc0 = (t & 15) * 4;   // 0,4,...,60

    // ---- 1D kernel = row sums of 2D kernel (identical per channel) ----
    if (t < K) {
        float s = 0.f;
        const float* kr = kern + t * K;
        #pragma unroll
        for (int j = 0; j < K; ++j) s += kr[j];
        s_k1[t] = s;
    }

    // ---- mask + unconditional img prefetch (copy path uses directly,
    //      blur path reuses as blend iv) ----
    const size_t HW = (size_t)HH * WW;
    const size_t pix0 = (size_t)(y0 + hr) * WW + (x0 + hc0);
    float4 mv = *(const float4*)(mask + pix0);
    float4 i0 = *(const float4*)(img + pix0);
    float4 i1 = *(const float4*)(img + HW + pix0);
    float4 i2 = *(const float4*)(img + 2 * HW + pix0);

    int anyLocal = (mv.x != 0.f) | (mv.y != 0.f) | (mv.z != 0.f) | (mv.w != 0.f);
    int any = __syncthreads_or(anyLocal);   // also publishes s_k1

    if (!any) {
        // pure copy: out = img * 255, interleave in regs, 3 aligned float4
        float* ob = out + pix0 * 3;
        *(float4*)(ob)     = make_float4(i0.x * 255.f, i1.x * 255.f, i2.x * 255.f, i0.y * 255.f);
        *(float4*)(ob + 4) = make_float4(i1.y * 255.f, i2.y * 255.f, i0.z * 255.f, i1.z * 255.f);
        *(float4*)(ob + 8) = make_float4(i2.z * 255.f, i0.w * 255.f, i1.w * 255.f, i2.w * 255.f);
        return;
    }

    // taps -> SGPRs (wave-uniform)
    float k1r[K];
    #pragma unroll
    for (int j = 0; j < K; ++j) k1r[j] = uniformf(s_k1[j]);

    // interior tile: whole halo in-bounds
    const bool interior = (tx >= 1) && (tx <= 58) && (ty >= 1) && (ty <= 133);

    // staging: 240 active threads = 10 rows x 24 float4-cols per round
    const int sr  = t / 24;
    const int sc  = t % 24;
    const bool sact = (t < 240);

    auto stage = [&](int ch) {
        const float* gp0 = img + (size_t)ch * HW
                         + (size_t)(y0 - RAD + sr) * WW + (x0 - 16 + 4 * sc);
        float* lp0 = s_in + sr * IW + 4 * sc;
        if (interior) {
            if (sact) {
                #pragma unroll
                for (int k2 = 0; k2 < 5; ++k2) {
                    if (sr + 10 * k2 < IH)
                        GLDS(gp0 + (size_t)(10 * k2) * WW, lp0 + 10 * k2 * IW);
                }
            }
        } else {
            #pragma unroll
            for (int k2 = 0; k2 < 5; ++k2) {
                int r = sr + 10 * k2;
                if (sact && r < IH) {
                    int gy = y0 - RAD + r, gx = x0 - 16 + 4 * sc;
                    float4 v = make_float4(0.f, 0.f, 0.f, 0.f);
                    if (gy >= 0 && gy < HH && gx >= 0 && gx < WW)
                        v = *(const float4*)(img + (size_t)ch * HW + (size_t)gy * WW + gx);
                    *(float4*)(s_in + r * IW + 4 * sc) = v;
                }
            }
        }
    };

    stage(0);

    float o[12];   // final interleaved pixels, built per channel

    // V-pass mapping: 192 active threads, each = (column, 8-row half)
    const int vc = t % 96;       // column 0..95
    const int vh = t / 96;       // 0,1 active; 2 = idle (t >= 192)

    #pragma unroll
    for (int ch = 0; ch < 3; ++ch) {
        __syncthreads();   // staging(ch) done; prev H-pass s_tmpT reads done

        // ---- vertical pass: stream 38 rows once, 8 running accumulators;
        //      write TRANSPOSED (stride 17 -> conflict-free scalar writes) ----
        if (vh < 2) {
            float acc[8] = {0.f, 0.f, 0.f, 0.f, 0.f, 0.f, 0.f, 0.f};
            const int ybase = vh * 8;
            #pragma unroll
            for (int s = 0; s < 38; ++s) {
                float v = s_in[(ybase + s) * IW + vc];
                #pragma unroll
                for (int j = 0; j < 8; ++j) {
                    if (s - j >= 0 && s - j <= 30) acc[j] += v * k1r[s - j];
                }
            }
            float* cp = s_tmpT + vc * TSTR + ybase;
            #pragma unroll
            for (int j = 0; j < 8; ++j) cp[j] = acc[j];
        }

        __syncthreads();   // s_tmpT ready; s_in free

        if (ch < 2) stage(ch + 1);   // HBM latency hides under H-pass

        // ---- horizontal pass: 34 stride-17 scalar reads (conflict-free),
        //      4 sliding-window outputs/thread ----
        float a0 = 0.f, a1 = 0.f, a2 = 0.f, a3 = 0.f;
        const float* colp = s_tmpT + (hc0 + 1) * TSTR + hr;
        #pragma unroll
        for (int u = 0; u < 34; ++u) {
            float v = colp[u * TSTR];
            if (u <= 30)           a0 += v * k1r[u];
            if (u >= 1 && u <= 31) a1 += v * k1r[u - 1];
            if (u >= 2 && u <= 32) a2 += v * k1r[u - 2];
            if (u >= 3)            a3 += v * k1r[u - 3];
        }

        // ---- blend this channel into interleaved output registers ----
        float4 iv = (ch == 0) ? i0 : (ch == 1) ? i1 : i2;
        float bl[4] = {a0, a1, a2, a3};
        #pragma unroll
        for (int p = 0; p < 4; ++p) {
            float m = fcomp(mv, p);
            o[p * 3 + ch] = (fcomp(iv, p) * (1.f - m) + bl[p] * m) * 255.f;
        }
    }

    // ---- 3 aligned float4 stores (full-line coalesced) ----
    float* ob = out + pix0 * 3;
    *(float4*)(ob)     = make_float4(o[0], o[1], o[2],  o[3]);
    *(float4*)(ob + 4) = make_float4(o[4], o[5], o[6],  o[7]);
    *(float4*)(ob + 8) = make_float4(o[8], o[9], o[10], o[11]);
}

extern "C" void kernel_launch(void* const* d_in, const int* in_sizes, int n_in,
                              void* d_out, int out_size, void* d_ws, size_t ws_size,
                              hipStream_t stream) {
    const float* img  = (const float*)d_in[0];
    const float* mask = (const float*)d_in[1];
    const float* kern = (const float*)d_in[2];
    float* out = (float*)d_out;
    int nblocks = 60 * 135;  // 8100
    blur_masked_kernel<<<nblocks, NTHREADS, 0, stream>>>(img, mask, kern, out);
}